// Round 1
// baseline (595.818 us; speedup 1.0000x reference)
//
#include <hip/hip_runtime.h>
#include <hip/hip_bf16.h>

// Problem constants
#define HW 16384        // 128*128
#define IMGW 128
#define Bsz 2
#define Cc 192          // channels
#define NH 4            // heads
#define CH 48           // channels per head
static const size_t CP = (size_t)Cc * HW;   // one batch's 192-channel block = 3,145,728 floats

typedef __attribute__((ext_vector_type(4))) float f32x4;

// ---------------------------------------------------------------------------
// conv1x1 as GEMM: out[b][o][n] = sum_c w[o][c] * in[b][c][n]
// 64x64 tile, 256 threads, each thread 4x4 via f32x4 LDS fragments.
// ---------------------------------------------------------------------------
__global__ __launch_bounds__(256) void conv1x1_kernel(
    const float* __restrict__ in, const float* __restrict__ wgt,
    float* __restrict__ out, int Cin, int Cout) {
  __shared__ __align__(16) float Ws[16][68];  // [c][o], padded
  __shared__ __align__(16) float Xs[16][68];  // [c][n], padded
  const int b = blockIdx.z;
  const int o0 = blockIdx.y * 64;
  const int n0 = blockIdx.x * 64;
  const int tid = threadIdx.x;
  const int tx = tid & 15, ty = tid >> 4;
  const float* inb = in + (size_t)b * Cin * HW;
  float acc[4][4] = {};
  for (int c0 = 0; c0 < Cin; c0 += 16) {
    #pragma unroll
    for (int e = 0; e < 4; ++e) {
      int idx = tid + e * 256;          // 0..1023
      int oo = idx >> 4, cc = idx & 15;
      Ws[cc][oo] = wgt[(size_t)(o0 + oo) * Cin + (c0 + cc)];
    }
    {
      int cc = tid >> 4, nn = (tid & 15) * 4;
      *(f32x4*)&Xs[cc][nn] = *(const f32x4*)&inb[(size_t)(c0 + cc) * HW + n0 + nn];
    }
    __syncthreads();
    #pragma unroll
    for (int kk = 0; kk < 16; ++kk) {
      f32x4 wv = *(f32x4*)&Ws[kk][ty * 4];
      f32x4 xv = *(f32x4*)&Xs[kk][tx * 4];
      #pragma unroll
      for (int i = 0; i < 4; ++i)
        #pragma unroll
        for (int j = 0; j < 4; ++j)
          acc[i][j] += wv[i] * xv[j];
    }
    __syncthreads();
  }
  #pragma unroll
  for (int i = 0; i < 4; ++i) {
    int o = o0 + ty * 4 + i;
    f32x4 r;
    #pragma unroll
    for (int j = 0; j < 4; ++j) r[j] = acc[i][j];
    *(f32x4*)&out[((size_t)b * Cout + o) * HW + n0 + tx * 4] = r;
  }
}

// ---------------------------------------------------------------------------
// depthwise 3x3, SAME zero padding. One thread per output pixel.
// ---------------------------------------------------------------------------
__global__ __launch_bounds__(256) void dwconv_kernel(
    const float* __restrict__ in, const float* __restrict__ wgt,
    float* __restrict__ out, int Ctot) {
  const int b = blockIdx.z, ch = blockIdx.y;
  const int n = blockIdx.x * 256 + threadIdx.x;
  const int y = n >> 7, x = n & 127;
  const float* ip = in + ((size_t)b * Ctot + ch) * HW;
  const float* wp = wgt + ch * 9;
  float acc = 0.f;
  #pragma unroll
  for (int dy = -1; dy <= 1; ++dy) {
    int yy = y + dy;
    if (yy < 0 || yy > IMGW - 1) continue;
    #pragma unroll
    for (int dx = -1; dx <= 1; ++dx) {
      int xx = x + dx;
      if (xx < 0 || xx > IMGW - 1) continue;
      acc += wp[(dy + 1) * 3 + (dx + 1)] * ip[yy * IMGW + xx];
    }
  }
  out[((size_t)b * Ctot + ch) * HW + n] = acc;
}

// ---------------------------------------------------------------------------
// L2 norm over HW per (b, channel-row): inv[row] = 1/max(||x||, 1e-12)
// in has per-batch stride bstride; 192 rows per batch.
// ---------------------------------------------------------------------------
__global__ __launch_bounds__(256) void norm_kernel(
    const float* __restrict__ in, size_t bstride, float* __restrict__ inv) {
  const int row = blockIdx.x;               // 0..Bsz*192-1
  const int b = row / Cc, r = row % Cc;
  const float* p = in + (size_t)b * bstride + (size_t)r * HW;
  float s = 0.f;
  for (int i = threadIdx.x; i < HW; i += 256) {
    float v = p[i];
    s += v * v;
  }
  #pragma unroll
  for (int off = 32; off; off >>= 1) s += __shfl_down(s, off);
  __shared__ float red[4];
  if ((threadIdx.x & 63) == 0) red[threadIdx.x >> 6] = s;
  __syncthreads();
  if (threadIdx.x == 0) {
    float t = red[0] + red[1] + red[2] + red[3];
    inv[row] = 1.f / fmaxf(sqrtf(t), 1e-12f);
  }
}

// ---------------------------------------------------------------------------
// QK^T partial sums. grid (32 n-chunks, 8 bh). Each block: 48x48 dots over
// its 512-wide n-chunk; thread owns 9 (i,j) pairs. Deterministic two-phase.
// ---------------------------------------------------------------------------
__global__ __launch_bounds__(256) void attn_partial_kernel(
    const float* __restrict__ q, size_t qbs,
    const float* __restrict__ k, size_t kbs,
    float* __restrict__ spart) {
  const int bh = blockIdx.y;
  const int b = bh >> 2, hd = bh & 3;
  const int chunk = blockIdx.x;
  const float* qp = q + (size_t)b * qbs + (size_t)(hd * CH) * HW + chunk * 512;
  const float* kp = k + (size_t)b * kbs + (size_t)(hd * CH) * HW + chunk * 512;
  __shared__ float Qs[48][65];
  __shared__ float Ks[48][65];
  const int tid = threadIdx.x;
  int ii[9], jj[9];
  #pragma unroll
  for (int p = 0; p < 9; ++p) {
    int pi = tid + p * 256;
    ii[p] = pi / 48;
    jj[p] = pi - ii[p] * 48;
  }
  float acc[9] = {};
  for (int s0 = 0; s0 < 512; s0 += 64) {
    for (int e = tid; e < 3072; e += 256) {
      int r = e >> 6, nn = e & 63;
      Qs[r][nn] = qp[(size_t)r * HW + s0 + nn];
      Ks[r][nn] = kp[(size_t)r * HW + s0 + nn];
    }
    __syncthreads();
    #pragma unroll 4
    for (int nn = 0; nn < 64; ++nn) {
      #pragma unroll
      for (int p = 0; p < 9; ++p)
        acc[p] += Qs[ii[p]][nn] * Ks[jj[p]][nn];
    }
    __syncthreads();
  }
  #pragma unroll
  for (int p = 0; p < 9; ++p) {
    int pi = tid + p * 256;
    spart[((size_t)bh * 32 + chunk) * 2304 + pi] = acc[p];
  }
}

// ---------------------------------------------------------------------------
// Reduce partials, scale by inv norms * temperature, softmax over j (48).
// One wave per (bh, i) row.
// ---------------------------------------------------------------------------
__global__ __launch_bounds__(64) void attn_finalize_kernel(
    const float* __restrict__ spart,
    const float* __restrict__ invq, const float* __restrict__ invk,
    const float* __restrict__ temp, float* __restrict__ attn) {
  const int row = blockIdx.x;               // bh*48 + i
  const int bh = row / 48, i = row % 48;
  const int b = bh >> 2, hd = bh & 3;
  const int j = threadIdx.x;
  float s;
  if (j < 48) {
    float t = 0.f;
    for (int ch = 0; ch < 32; ++ch)
      t += spart[((size_t)bh * 32 + ch) * 2304 + i * 48 + j];
    s = t * invq[b * Cc + hd * CH + i] * invk[b * Cc + hd * CH + j] * temp[hd];
  } else {
    s = -1e30f;
  }
  float m = s;
  #pragma unroll
  for (int off = 32; off; off >>= 1) m = fmaxf(m, __shfl_xor(m, off));
  float e = (j < 48) ? expf(s - m) : 0.f;
  float sum = e;
  #pragma unroll
  for (int off = 32; off; off >>= 1) sum += __shfl_xor(sum, off);
  if (j < 48) attn[(size_t)bh * 2304 + i * 48 + j] = e / sum;
}

// ---------------------------------------------------------------------------
// out[i][n] = sum_j attn[i][j] * v[j][n]. attn in LDS (broadcast), v in regs.
// ---------------------------------------------------------------------------
__global__ __launch_bounds__(256) void attn_apply_kernel(
    const float* __restrict__ attn,
    const float* __restrict__ v, size_t vbs,
    float* __restrict__ out, size_t obs) {
  const int bh = blockIdx.y;
  const int b = bh >> 2, hd = bh & 3;
  const int n = blockIdx.x * 256 + threadIdx.x;
  const float* vp = v + (size_t)b * vbs + (size_t)(hd * CH) * HW + n;
  float* op = out + (size_t)b * obs + (size_t)(hd * CH) * HW + n;
  __shared__ __align__(16) float As[48][48];
  const int tid = threadIdx.x;
  for (int e = tid; e < 2304; e += 256) As[e / 48][e % 48] = attn[(size_t)bh * 2304 + e];
  __syncthreads();
  float vv[48];
  #pragma unroll
  for (int j = 0; j < 48; ++j) vv[j] = vp[(size_t)j * HW];
  #pragma unroll 1
  for (int i = 0; i < 48; ++i) {
    const f32x4* arow = (const f32x4*)&As[i][0];
    float acc = 0.f;
    #pragma unroll
    for (int j4 = 0; j4 < 12; ++j4) {
      f32x4 a = arow[j4];
      acc += a[0] * vv[j4 * 4 + 0] + a[1] * vv[j4 * 4 + 1] +
             a[2] * vv[j4 * 4 + 2] + a[3] * vv[j4 * 4 + 3];
    }
    op[(size_t)i * HW] = acc;
  }
}

// ---------------------------------------------------------------------------
extern "C" void kernel_launch(void* const* d_in, const int* in_sizes, int n_in,
                              void* d_out, int out_size, void* d_ws, size_t ws_size,
                              hipStream_t stream) {
  const float* x      = (const float*)d_in[0];
  const float* y      = (const float*)d_in[1];
  const float* qkv_w  = (const float*)d_in[2];
  const float* dw_w   = (const float*)d_in[3];
  const float* kv_w   = (const float*)d_in[4];
  const float* proj_w = (const float*)d_in[5];
  const float* temp   = (const float*)d_in[6];
  float* out = (float*)d_out;
  float* ws  = (float*)d_ws;

  const size_t SF = (size_t)Bsz * CP;       // 6,291,456 floats per full tensor
  float* qkv_pre = ws;                      // [0, 3*SF)
  float* qkv     = ws + 3 * SF;             // [3*SF, 6*SF)
  float* kvb     = ws;                      // reuse qkv_pre region: [0, 2*SF)
  float* q1      = ws + 2 * SF;             // [2*SF, 3*SF)
  float* o2      = ws + 6 * SF;             // [6*SF, 7*SF)
  float* invq    = ws + 7 * SF;
  float* invk    = invq + Bsz * Cc;
  float* spart   = invk + Bsz * Cc;         // 8*32*2304 = 589,824
  float* attn    = spart + 8 * 32 * 2304;   // 18,432

  dim3 blk(256);

  // 1. qkv_pre = conv1x1(x, qkv_w)   [2,576,HW]
  conv1x1_kernel<<<dim3(HW / 64, 576 / 64, Bsz), blk, 0, stream>>>(
      x, qkv_w, qkv_pre, Cc, 3 * Cc);
  // 2. qkv = dwconv3x3(qkv_pre)
  dwconv_kernel<<<dim3(HW / 256, 3 * Cc, Bsz), blk, 0, stream>>>(
      qkv_pre, dw_w, qkv, 3 * Cc);
  // 3. kv = conv1x1(y, kv_w)   [2,384,HW]
  conv1x1_kernel<<<dim3(HW / 64, 384 / 64, Bsz), blk, 0, stream>>>(
      y, kv_w, kvb, Cc, 2 * Cc);

  // 4. mdta1: q = qkv[:,0:192], k2 = kvb[:,0:192], v2 = kvb[:,192:384]
  norm_kernel<<<dim3(Bsz * Cc), blk, 0, stream>>>(qkv, 3 * CP, invq);
  norm_kernel<<<dim3(Bsz * Cc), blk, 0, stream>>>(kvb, 2 * CP, invk);
  attn_partial_kernel<<<dim3(32, 8), blk, 0, stream>>>(qkv, 3 * CP, kvb, 2 * CP, spart);
  attn_finalize_kernel<<<dim3(8 * 48), dim3(64), 0, stream>>>(spart, invq, invk, temp, attn);
  attn_apply_kernel<<<dim3(HW / 256, 8), blk, 0, stream>>>(attn, kvb + CP, 2 * CP, q1, CP);

  // 5. mdta2: q = q1, k = qkv[:,192:384], v = qkv[:,384:576]
  norm_kernel<<<dim3(Bsz * Cc), blk, 0, stream>>>(q1, CP, invq);
  norm_kernel<<<dim3(Bsz * Cc), blk, 0, stream>>>(qkv + CP, 3 * CP, invk);
  attn_partial_kernel<<<dim3(32, 8), blk, 0, stream>>>(q1, CP, qkv + CP, 3 * CP, spart);
  attn_finalize_kernel<<<dim3(8 * 48), dim3(64), 0, stream>>>(spart, invq, invk, temp, attn);
  attn_apply_kernel<<<dim3(HW / 256, 8), blk, 0, stream>>>(attn, qkv + 2 * CP, 3 * CP, o2, CP);

  // 6. out = conv1x1(o2, proj_w)
  conv1x1_kernel<<<dim3(HW / 64, Cc / 64, Bsz), blk, 0, stream>>>(
      o2, proj_w, out, Cc, Cc);
}

// Round 2
// 458.103 us; speedup vs baseline: 1.3006x; 1.3006x over previous
//
#include <hip/hip_runtime.h>
#include <hip/hip_bf16.h>

// Problem constants
#define HW 16384        // 128*128
#define IMGW 128
#define Bsz 2
#define Cc 192          // channels
#define NH 4            // heads
#define CH 48           // channels per head
static const size_t CP = (size_t)Cc * HW;   // one batch's 192-channel block

typedef __attribute__((ext_vector_type(4))) float f32x4;
typedef __attribute__((ext_vector_type(8))) short short8;      // 8 bf16 (MFMA frag)
typedef __attribute__((ext_vector_type(8))) unsigned short ushort8;

__device__ __forceinline__ short f2bf(float f) {
  __hip_bfloat16 h = __float2bfloat16(f);
  return *reinterpret_cast<short*>(&h);
}

// ---------------------------------------------------------------------------
// Cast fp32 [b][192][HW] -> bf16 transposed [b][HW][192].
// grid (HW/256, 192/8, Bsz), block 256. Thread owns one hw, 8 channels.
// ---------------------------------------------------------------------------
__global__ __launch_bounds__(256) void cast_transpose_kernel(
    const float* __restrict__ in, short* __restrict__ outt) {
  const int b = blockIdx.z;
  const int c0 = blockIdx.y * 8;
  const int hw = blockIdx.x * 256 + threadIdx.x;
  const float* ib = in + (size_t)b * CP;
  ushort8 u;
  #pragma unroll
  for (int j = 0; j < 8; ++j)
    u[j] = (unsigned short)f2bf(ib[(size_t)(c0 + j) * HW + hw]);
  *(ushort8*)&outt[(size_t)b * CP + (size_t)hw * Cc + c0] = u;
}

// elementwise fp32 -> bf16 (weights)
__global__ __launch_bounds__(256) void cast_w_kernel(
    const float* __restrict__ w, short* __restrict__ wb, int n) {
  int i = blockIdx.x * 256 + threadIdx.x;
  if (i < n) wb[i] = f2bf(w[i]);
}

// ---------------------------------------------------------------------------
// conv1x1 as bf16 MFMA GEMM.
// D[m=hw][n=o] = sum_c Xt[hw][c] * W[o][c]   (B = W^T, both frags contiguous)
// Block 256 thr = 4 waves (2m x 2n), tile 128(hw) x 64(o), K=192 in 3 steps.
// ---------------------------------------------------------------------------
#define BMH 128
#define BNO 64
#define BKC 64
#define PADK 72   // 144B row stride = 4-bank step -> conflict-free b128 reads

__global__ __launch_bounds__(256) void conv_mfma_kernel(
    const short* __restrict__ xt,   // [b][HW][192] bf16
    const short* __restrict__ wb,   // [Cout][192] bf16
    float* __restrict__ out, int Cout) {
  __shared__ __align__(16) short As[BMH * PADK];
  __shared__ __align__(16) short Bs[BNO * PADK];
  const int b = blockIdx.z;
  const int hw0 = blockIdx.x * BMH;
  const int o0 = blockIdx.y * BNO;
  const int tid = threadIdx.x;
  const int lane = tid & 63, wid = tid >> 6;
  const int wm = wid & 1, wn = wid >> 1;     // wave quadrant
  const short* xtb = xt + (size_t)b * CP + (size_t)hw0 * Cc;
  const short* wbb = wb + (size_t)o0 * Cc;
  f32x4 acc[4][2] = {};
  for (int k0 = 0; k0 < Cc; k0 += BKC) {
    #pragma unroll
    for (int p = 0; p < 4; ++p) {            // A: 128x64 = 1024 chunks
      int i = tid + p * 256;
      int row = i >> 3, cc = i & 7;
      short8 v = *(const short8*)(xtb + (size_t)row * Cc + k0 + cc * 8);
      *(short8*)&As[row * PADK + cc * 8] = v;
    }
    #pragma unroll
    for (int p = 0; p < 2; ++p) {            // B: 64x64 = 512 chunks
      int i = tid + p * 256;
      int row = i >> 3, cc = i & 7;
      short8 v = *(const short8*)(wbb + (size_t)row * Cc + k0 + cc * 8);
      *(short8*)&Bs[row * PADK + cc * 8] = v;
    }
    __syncthreads();
    #pragma unroll
    for (int ks = 0; ks < 2; ++ks) {
      short8 bfrag[2];
      #pragma unroll
      for (int fn = 0; fn < 2; ++fn)
        bfrag[fn] = *(short8*)&Bs[(wn * 32 + fn * 16 + (lane & 15)) * PADK +
                                  ks * 32 + (lane >> 4) * 8];
      #pragma unroll
      for (int fm = 0; fm < 4; ++fm) {
        short8 afrag = *(short8*)&As[(wm * 64 + fm * 16 + (lane & 15)) * PADK +
                                     ks * 32 + (lane >> 4) * 8];
        #pragma unroll
        for (int fn = 0; fn < 2; ++fn)
          acc[fm][fn] = __builtin_amdgcn_mfma_f32_16x16x32_bf16(
              afrag, bfrag[fn], acc[fm][fn], 0, 0, 0);
      }
    }
    __syncthreads();
  }
  // epilogue: D col=lane&15 -> o, row=(lane>>4)*4+reg -> hw (contiguous f32x4)
  #pragma unroll
  for (int fm = 0; fm < 4; ++fm)
    #pragma unroll
    for (int fn = 0; fn < 2; ++fn) {
      int o = o0 + wn * 32 + fn * 16 + (lane & 15);
      int hw = hw0 + wm * 64 + fm * 16 + ((lane >> 4) << 2);
      *(f32x4*)&out[((size_t)b * Cout + o) * HW + hw] = acc[fm][fn];
    }
}

// ---------------------------------------------------------------------------
// depthwise 3x3, SAME zero padding. One thread per output pixel.
// ---------------------------------------------------------------------------
__global__ __launch_bounds__(256) void dwconv_kernel(
    const float* __restrict__ in, const float* __restrict__ wgt,
    float* __restrict__ out, int Ctot) {
  const int b = blockIdx.z, ch = blockIdx.y;
  const int n = blockIdx.x * 256 + threadIdx.x;
  const int y = n >> 7, x = n & 127;
  const float* ip = in + ((size_t)b * Ctot + ch) * HW;
  const float* wp = wgt + ch * 9;
  float acc = 0.f;
  #pragma unroll
  for (int dy = -1; dy <= 1; ++dy) {
    int yy = y + dy;
    if (yy < 0 || yy > IMGW - 1) continue;
    #pragma unroll
    for (int dx = -1; dx <= 1; ++dx) {
      int xx = x + dx;
      if (xx < 0 || xx > IMGW - 1) continue;
      acc += wp[(dy + 1) * 3 + (dx + 1)] * ip[yy * IMGW + xx];
    }
  }
  out[((size_t)b * Ctot + ch) * HW + n] = acc;
}

// ---------------------------------------------------------------------------
// L2 norm over HW per (b, channel-row): inv[row] = 1/max(||x||, 1e-12)
// ---------------------------------------------------------------------------
__global__ __launch_bounds__(256) void norm_kernel(
    const float* __restrict__ in, size_t bstride, float* __restrict__ inv) {
  const int row = blockIdx.x;
  const int b = row / Cc, r = row % Cc;
  const float* p = in + (size_t)b * bstride + (size_t)r * HW;
  float s = 0.f;
  for (int i = threadIdx.x; i < HW; i += 256) {
    float v = p[i];
    s += v * v;
  }
  #pragma unroll
  for (int off = 32; off; off >>= 1) s += __shfl_down(s, off);
  __shared__ float red[4];
  if ((threadIdx.x & 63) == 0) red[threadIdx.x >> 6] = s;
  __syncthreads();
  if (threadIdx.x == 0) {
    float t = red[0] + red[1] + red[2] + red[3];
    inv[row] = 1.f / fmaxf(sqrtf(t), 1e-12f);
  }
}

// ---------------------------------------------------------------------------
// QK^T partial sums. grid (32 n-chunks, 8 bh).
// ---------------------------------------------------------------------------
__global__ __launch_bounds__(256) void attn_partial_kernel(
    const float* __restrict__ q, size_t qbs,
    const float* __restrict__ k, size_t kbs,
    float* __restrict__ spart) {
  const int bh = blockIdx.y;
  const int b = bh >> 2, hd = bh & 3;
  const int chunk = blockIdx.x;
  const float* qp = q + (size_t)b * qbs + (size_t)(hd * CH) * HW + chunk * 512;
  const float* kp = k + (size_t)b * kbs + (size_t)(hd * CH) * HW + chunk * 512;
  __shared__ float Qs[48][65];
  __shared__ float Ks[48][65];
  const int tid = threadIdx.x;
  int ii[9], jj[9];
  #pragma unroll
  for (int p = 0; p < 9; ++p) {
    int pi = tid + p * 256;
    ii[p] = pi / 48;
    jj[p] = pi - ii[p] * 48;
  }
  float acc[9] = {};
  for (int s0 = 0; s0 < 512; s0 += 64) {
    for (int e = tid; e < 3072; e += 256) {
      int r = e >> 6, nn = e & 63;
      Qs[r][nn] = qp[(size_t)r * HW + s0 + nn];
      Ks[r][nn] = kp[(size_t)r * HW + s0 + nn];
    }
    __syncthreads();
    #pragma unroll 4
    for (int nn = 0; nn < 64; ++nn) {
      #pragma unroll
      for (int p = 0; p < 9; ++p)
        acc[p] += Qs[ii[p]][nn] * Ks[jj[p]][nn];
    }
    __syncthreads();
  }
  #pragma unroll
  for (int p = 0; p < 9; ++p) {
    int pi = tid + p * 256;
    spart[((size_t)bh * 32 + chunk) * 2304 + pi] = acc[p];
  }
}

// ---------------------------------------------------------------------------
// Reduce partials, scale, softmax over j (48). One wave per (bh, i) row.
// ---------------------------------------------------------------------------
__global__ __launch_bounds__(64) void attn_finalize_kernel(
    const float* __restrict__ spart,
    const float* __restrict__ invq, const float* __restrict__ invk,
    const float* __restrict__ temp, float* __restrict__ attn) {
  const int row = blockIdx.x;
  const int bh = row / 48, i = row % 48;
  const int b = bh >> 2, hd = bh & 3;
  const int j = threadIdx.x;
  float s;
  if (j < 48) {
    float t = 0.f;
    for (int ch = 0; ch < 32; ++ch)
      t += spart[((size_t)bh * 32 + ch) * 2304 + i * 48 + j];
    s = t * invq[b * Cc + hd * CH + i] * invk[b * Cc + hd * CH + j] * temp[hd];
  } else {
    s = -1e30f;
  }
  float m = s;
  #pragma unroll
  for (int off = 32; off; off >>= 1) m = fmaxf(m, __shfl_xor(m, off));
  float e = (j < 48) ? expf(s - m) : 0.f;
  float sum = e;
  #pragma unroll
  for (int off = 32; off; off >>= 1) sum += __shfl_xor(sum, off);
  if (j < 48) attn[(size_t)bh * 2304 + i * 48 + j] = e / sum;
}

// ---------------------------------------------------------------------------
// out[i][n] = sum_j attn[i][j] * v[j][n].
// BF16T=0: fp32 out [c][hw].  BF16T=1: bf16 transposed outt [hw][c].
// ---------------------------------------------------------------------------
template <int BF16T>
__global__ __launch_bounds__(256) void attn_apply_kernel(
    const float* __restrict__ attn,
    const float* __restrict__ v, size_t vbs,
    float* __restrict__ out, size_t obs, short* __restrict__ outt) {
  const int bh = blockIdx.y;
  const int b = bh >> 2, hd = bh & 3;
  const int n = blockIdx.x * 256 + threadIdx.x;
  const float* vp = v + (size_t)b * vbs + (size_t)(hd * CH) * HW + n;
  __shared__ __align__(16) float As[48][48];
  const int tid = threadIdx.x;
  for (int e = tid; e < 2304; e += 256) As[e / 48][e % 48] = attn[(size_t)bh * 2304 + e];
  __syncthreads();
  float vv[48];
  #pragma unroll
  for (int j = 0; j < 48; ++j) vv[j] = vp[(size_t)j * HW];
  if (BF16T == 0) {
    float* op = out + (size_t)b * obs + (size_t)(hd * CH) * HW + n;
    #pragma unroll 1
    for (int i = 0; i < 48; ++i) {
      const f32x4* arow = (const f32x4*)&As[i][0];
      float acc = 0.f;
      #pragma unroll
      for (int j4 = 0; j4 < 12; ++j4) {
        f32x4 a = arow[j4];
        acc += a[0] * vv[j4 * 4 + 0] + a[1] * vv[j4 * 4 + 1] +
               a[2] * vv[j4 * 4 + 2] + a[3] * vv[j4 * 4 + 3];
      }
      op[(size_t)i * HW] = acc;
    }
  } else {
    short* tp = outt + (size_t)b * CP + (size_t)n * Cc + hd * CH;
    #pragma unroll 1
    for (int io = 0; io < 6; ++io) {
      ushort8 u;
      #pragma unroll
      for (int e = 0; e < 8; ++e) {
        const f32x4* arow = (const f32x4*)&As[io * 8 + e][0];
        float acc = 0.f;
        #pragma unroll
        for (int j4 = 0; j4 < 12; ++j4) {
          f32x4 a = arow[j4];
          acc += a[0] * vv[j4 * 4 + 0] + a[1] * vv[j4 * 4 + 1] +
                 a[2] * vv[j4 * 4 + 2] + a[3] * vv[j4 * 4 + 3];
        }
        u[e] = (unsigned short)f2bf(acc);
      }
      *(ushort8*)&tp[io * 8] = u;
    }
  }
}

// ---------------------------------------------------------------------------
extern "C" void kernel_launch(void* const* d_in, const int* in_sizes, int n_in,
                              void* d_out, int out_size, void* d_ws, size_t ws_size,
                              hipStream_t stream) {
  const float* x      = (const float*)d_in[0];
  const float* y      = (const float*)d_in[1];
  const float* qkv_w  = (const float*)d_in[2];
  const float* dw_w   = (const float*)d_in[3];
  const float* kv_w   = (const float*)d_in[4];
  const float* proj_w = (const float*)d_in[5];
  const float* temp   = (const float*)d_in[6];
  float* out = (float*)d_out;
  float* ws  = (float*)d_ws;

  const size_t SF = (size_t)Bsz * CP;       // 6,291,456 floats per full tensor
  float* qkv_pre = ws;                      // [0, 3SF)
  float* qkv     = ws + 3 * SF;             // [3SF, 6SF)
  float* kvb     = ws;                      // reuse: [0, 2SF)
  float* q1      = ws + 2 * SF;             // [2SF, 3SF)
  short* xt      = (short*)(ws + 6 * SF);            // SF shorts
  short* yt      = (short*)(ws + 6 * SF) + SF;       // SF shorts -> ends at 7SF
  short* o2t     = (short*)(ws + 6 * SF);            // reuse xt region (xt dead)
  float* invq    = ws + 7 * SF;
  float* invk    = invq + Bsz * Cc;
  float* spart   = invk + Bsz * Cc;         // 8*32*2304
  float* attn    = spart + 8 * 32 * 2304;   // 18,432
  short* wqkv    = (short*)(attn + 8 * 2304);
  short* wkv     = wqkv + 576 * Cc;
  short* wproj   = wkv + 384 * Cc;

  dim3 blk(256);

  // 0. casts
  cast_transpose_kernel<<<dim3(HW / 256, Cc / 8, Bsz), blk, 0, stream>>>(x, xt);
  cast_transpose_kernel<<<dim3(HW / 256, Cc / 8, Bsz), blk, 0, stream>>>(y, yt);
  cast_w_kernel<<<dim3((576 * Cc) / 256), blk, 0, stream>>>(qkv_w, wqkv, 576 * Cc);
  cast_w_kernel<<<dim3((384 * Cc) / 256), blk, 0, stream>>>(kv_w, wkv, 384 * Cc);
  cast_w_kernel<<<dim3((192 * Cc) / 256), blk, 0, stream>>>(proj_w, wproj, 192 * Cc);

  // 1. qkv_pre = conv1x1(x, qkv_w)
  conv_mfma_kernel<<<dim3(HW / BMH, 576 / BNO, Bsz), blk, 0, stream>>>(
      xt, wqkv, qkv_pre, 3 * Cc);
  // 2. qkv = dwconv3x3(qkv_pre)
  dwconv_kernel<<<dim3(HW / 256, 3 * Cc, Bsz), blk, 0, stream>>>(
      qkv_pre, dw_w, qkv, 3 * Cc);
  // 3. kv = conv1x1(y, kv_w)
  conv_mfma_kernel<<<dim3(HW / BMH, 384 / BNO, Bsz), blk, 0, stream>>>(
      yt, wkv, kvb, 2 * Cc);

  // 4. mdta1: q = qkv[:,0:192], k2 = kvb[:,0:192], v2 = kvb[:,192:384]
  norm_kernel<<<dim3(Bsz * Cc), blk, 0, stream>>>(qkv, 3 * CP, invq);
  norm_kernel<<<dim3(Bsz * Cc), blk, 0, stream>>>(kvb, 2 * CP, invk);
  attn_partial_kernel<<<dim3(32, 8), blk, 0, stream>>>(qkv, 3 * CP, kvb, 2 * CP, spart);
  attn_finalize_kernel<<<dim3(8 * 48), dim3(64), 0, stream>>>(spart, invq, invk, temp, attn);
  attn_apply_kernel<0><<<dim3(HW / 256, 8), blk, 0, stream>>>(
      attn, kvb + CP, 2 * CP, q1, CP, nullptr);

  // 5. mdta2: q = q1, k = qkv[:,192:384], v = qkv[:,384:576] -> o2t (bf16^T)
  norm_kernel<<<dim3(Bsz * Cc), blk, 0, stream>>>(q1, CP, invq);
  norm_kernel<<<dim3(Bsz * Cc), blk, 0, stream>>>(qkv + CP, 3 * CP, invk);
  attn_partial_kernel<<<dim3(32, 8), blk, 0, stream>>>(q1, CP, qkv + CP, 3 * CP, spart);
  attn_finalize_kernel<<<dim3(8 * 48), dim3(64), 0, stream>>>(spart, invq, invk, temp, attn);
  attn_apply_kernel<1><<<dim3(HW / 256, 8), blk, 0, stream>>>(
      attn, qkv + 2 * CP, 3 * CP, nullptr, 0, o2t);

  // 6. out = conv1x1(o2t, proj_w)
  conv_mfma_kernel<<<dim3(HW / BMH, Cc / BNO, Bsz), blk, 0, stream>>>(
      o2t, wproj, out, Cc);
}

// Round 4
// 184.791 us; speedup vs baseline: 3.2243x; 2.4790x over previous
//
#include <hip/hip_runtime.h>
#include <hip/hip_bf16.h>

// Problem constants
#define HW 16384        // 128*128
#define IMGW 128
#define Bsz 2
#define Cc 192          // channels
#define NH 4
#define CH 48
static const size_t CP = (size_t)Cc * HW;   // one batch's 192-channel block

typedef __attribute__((ext_vector_type(4))) float f32x4;
typedef __attribute__((ext_vector_type(8))) short short8;
typedef __attribute__((ext_vector_type(8))) unsigned short bf16x8;
typedef __attribute__((ext_vector_type(4))) unsigned short bf16x4;

__device__ __forceinline__ unsigned short f2bf(float f) {
  __hip_bfloat16 h = __float2bfloat16(f);
  return *reinterpret_cast<unsigned short*>(&h);
}
__device__ __forceinline__ float bf2f(unsigned short u) {
  union { unsigned int i; float f; } v;
  v.i = (unsigned int)u << 16;
  return v.f;
}

// ---------------------------------------------------------------------------
// Cast fp32 [b][192][HW] -> bf16 transposed [b][HW][192] (GEMM A-operand).
// ---------------------------------------------------------------------------
__global__ __launch_bounds__(256) void cast_transpose_kernel(
    const float* __restrict__ in, unsigned short* __restrict__ outt) {
  const int b = blockIdx.z;
  const int c0 = blockIdx.y * 8;
  const int hw = blockIdx.x * 256 + threadIdx.x;
  const float* ib = in + (size_t)b * CP;
  bf16x8 u;
  #pragma unroll
  for (int j = 0; j < 8; ++j)
    u[j] = f2bf(ib[(size_t)(c0 + j) * HW + hw]);
  *(bf16x8*)&outt[(size_t)b * CP + (size_t)hw * Cc + c0] = u;
}

__global__ __launch_bounds__(256) void cast_w_kernel(
    const float* __restrict__ w, unsigned short* __restrict__ wb, int n) {
  int i = blockIdx.x * 256 + threadIdx.x;
  if (i < n) wb[i] = f2bf(w[i]);
}

// ---------------------------------------------------------------------------
// conv1x1 bf16 MFMA GEMM. D[m=hw][n=o] = sum_c Xt[hw][c] * W[o][c]
// Tile 128(hw) x 64(o), 4 waves (2m x 2n). OUTBF16: store bf16 [c][hw].
// ---------------------------------------------------------------------------
#define BMH 128
#define BNO 64
#define BKC 64
#define PADK 72

template <int OUTBF16>
__global__ __launch_bounds__(256) void conv_mfma_kernel(
    const unsigned short* __restrict__ xt,   // [b][HW][192] bf16
    const unsigned short* __restrict__ wb,   // [Cout][192] bf16
    void* __restrict__ outv, int Cout) {
  __shared__ __align__(16) short As[BMH * PADK];
  __shared__ __align__(16) short Bs[BNO * PADK];
  const int b = blockIdx.z;
  const int hw0 = blockIdx.x * BMH;
  const int o0 = blockIdx.y * BNO;
  const int tid = threadIdx.x;
  const int lane = tid & 63, wid = tid >> 6;
  const int wm = wid & 1, wn = wid >> 1;
  const unsigned short* xtb = xt + (size_t)b * CP + (size_t)hw0 * Cc;
  const unsigned short* wbb = wb + (size_t)o0 * Cc;
  f32x4 acc[4][2] = {};
  for (int k0 = 0; k0 < Cc; k0 += BKC) {
    #pragma unroll
    for (int p = 0; p < 4; ++p) {
      int i = tid + p * 256;
      int row = i >> 3, cc = i & 7;
      *(short8*)&As[row * PADK + cc * 8] =
          *(const short8*)(xtb + (size_t)row * Cc + k0 + cc * 8);
    }
    #pragma unroll
    for (int p = 0; p < 2; ++p) {
      int i = tid + p * 256;
      int row = i >> 3, cc = i & 7;
      *(short8*)&Bs[row * PADK + cc * 8] =
          *(const short8*)(wbb + (size_t)row * Cc + k0 + cc * 8);
    }
    __syncthreads();
    #pragma unroll
    for (int ks = 0; ks < 2; ++ks) {
      short8 bfrag[2];
      #pragma unroll
      for (int fn = 0; fn < 2; ++fn)
        bfrag[fn] = *(short8*)&Bs[(wn * 32 + fn * 16 + (lane & 15)) * PADK +
                                  ks * 32 + (lane >> 4) * 8];
      #pragma unroll
      for (int fm = 0; fm < 4; ++fm) {
        short8 afrag = *(short8*)&As[(wm * 64 + fm * 16 + (lane & 15)) * PADK +
                                     ks * 32 + (lane >> 4) * 8];
        #pragma unroll
        for (int fn = 0; fn < 2; ++fn)
          acc[fm][fn] = __builtin_amdgcn_mfma_f32_16x16x32_bf16(
              afrag, bfrag[fn], acc[fm][fn], 0, 0, 0);
      }
    }
    __syncthreads();
  }
  #pragma unroll
  for (int fm = 0; fm < 4; ++fm)
    #pragma unroll
    for (int fn = 0; fn < 2; ++fn) {
      int o = o0 + wn * 32 + fn * 16 + (lane & 15);
      int hw = hw0 + wm * 64 + fm * 16 + ((lane >> 4) << 2);
      if (OUTBF16) {
        bf16x4 u;
        #pragma unroll
        for (int r = 0; r < 4; ++r) u[r] = f2bf(acc[fm][fn][r]);
        *(bf16x4*)&((unsigned short*)outv)[((size_t)b * Cout + o) * HW + hw] = u;
      } else {
        *(f32x4*)&((float*)outv)[((size_t)b * Cout + o) * HW + hw] = acc[fm][fn];
      }
    }
}

// ---------------------------------------------------------------------------
// depthwise 3x3 SAME, bf16 in/out, fp32 accum. 8 px/thread, bf16x8 I/O.
// grid (HW/2048, Ctot, Bsz)
// ---------------------------------------------------------------------------
__global__ __launch_bounds__(256) void dwconv_kernel(
    const unsigned short* __restrict__ in, const float* __restrict__ wgt,
    unsigned short* __restrict__ out, int Ctot) {
  const int b = blockIdx.z, ch = blockIdx.y;
  const int p0 = blockIdx.x * 2048 + threadIdx.x * 8;
  const int y = p0 >> 7, x0 = p0 & 127;
  const unsigned short* ip = in + ((size_t)b * Ctot + ch) * HW;
  const float* wp = wgt + ch * 9;
  float acc[8] = {};
  #pragma unroll
  for (int dy = -1; dy <= 1; ++dy) {
    int yy = y + dy;
    if (yy < 0 || yy > IMGW - 1) continue;
    const unsigned short* rp = ip + yy * IMGW;
    float r[10];
    bf16x8 mid = *(const bf16x8*)&rp[x0];
    #pragma unroll
    for (int e = 0; e < 8; ++e) r[e + 1] = bf2f(mid[e]);
    r[0] = (x0 > 0) ? bf2f(rp[x0 - 1]) : 0.f;
    r[9] = (x0 < 120) ? bf2f(rp[x0 + 8]) : 0.f;
    #pragma unroll
    for (int dx = 0; dx < 3; ++dx) {
      float wv = wp[(dy + 1) * 3 + dx];
      #pragma unroll
      for (int e = 0; e < 8; ++e) acc[e] += wv * r[e + dx];
    }
  }
  bf16x8 u;
  #pragma unroll
  for (int e = 0; e < 8; ++e) u[e] = f2bf(acc[e]);
  *(bf16x8*)&out[((size_t)b * Ctot + ch) * HW + p0] = u;
}

// ---------------------------------------------------------------------------
// L2 norm over HW per (b, channel): inv = 1/max(||x||,1e-12), bf16 input.
// ---------------------------------------------------------------------------
__global__ __launch_bounds__(256) void norm_kernel(
    const unsigned short* __restrict__ in, size_t bstride,
    float* __restrict__ inv) {
  const int row = blockIdx.x;
  const int b = row / Cc, r = row % Cc;
  const unsigned short* p = in + (size_t)b * bstride + (size_t)r * HW;
  float s = 0.f;
  for (int i = threadIdx.x * 8; i < HW; i += 2048) {
    bf16x8 u = *(const bf16x8*)&p[i];
    #pragma unroll
    for (int j = 0; j < 8; ++j) {
      float v = bf2f(u[j]);
      s += v * v;
    }
  }
  #pragma unroll
  for (int off = 32; off; off >>= 1) s += __shfl_down(s, off);
  __shared__ float red[4];
  if ((threadIdx.x & 63) == 0) red[threadIdx.x >> 6] = s;
  __syncthreads();
  if (threadIdx.x == 0) {
    float t = red[0] + red[1] + red[2] + red[3];
    inv[row] = 1.f / fmaxf(sqrtf(t), 1e-12f);
  }
}

// ---------------------------------------------------------------------------
// QK^T via MFMA. grid (64 n-chunks, 8 bh), 256 thr. Chunk = 256 n.
// Each wave: 9 MFMA (3x3 16-tiles) per 32-k-slice (its wid slice), 2 iters.
// Cross-wave LDS reduce -> spart[bh][chunk][2304].
// ---------------------------------------------------------------------------
#define PK 136
__global__ __launch_bounds__(256) void attn_qk_mfma(
    const unsigned short* __restrict__ q, size_t qbs,
    const unsigned short* __restrict__ k, size_t kbs,
    float* __restrict__ spart) {
  __shared__ __align__(16) char lds_raw[4 * 2304 * 4];
  short* Qs = (short*)lds_raw;          // 48*PK shorts
  short* Ks = Qs + 48 * PK;
  float* Rs = (float*)lds_raw;          // reused for reduce
  const int bh = blockIdx.y, b = bh >> 2, hd = bh & 3;
  const int n0 = blockIdx.x * 256;
  const int tid = threadIdx.x, lane = tid & 63, wid = tid >> 6;
  const unsigned short* qb = q + (size_t)b * qbs + (size_t)(hd * CH) * HW + n0;
  const unsigned short* kb = k + (size_t)b * kbs + (size_t)(hd * CH) * HW + n0;
  f32x4 acc[3][3] = {};
  #pragma unroll 1
  for (int it = 0; it < 2; ++it) {
    #pragma unroll
    for (int p = 0; p < 3; ++p) {
      int c = tid + p * 256;            // 0..767
      int row = c >> 4, col = c & 15;
      *(short8*)&Qs[row * PK + col * 8] =
          *(const short8*)(qb + (size_t)row * HW + it * 128 + col * 8);
      *(short8*)&Ks[row * PK + col * 8] =
          *(const short8*)(kb + (size_t)row * HW + it * 128 + col * 8);
    }
    __syncthreads();
    short8 af[3], bfr[3];
    #pragma unroll
    for (int t = 0; t < 3; ++t) {
      af[t]  = *(short8*)&Qs[(t * 16 + (lane & 15)) * PK + wid * 32 + (lane >> 4) * 8];
      bfr[t] = *(short8*)&Ks[(t * 16 + (lane & 15)) * PK + wid * 32 + (lane >> 4) * 8];
    }
    #pragma unroll
    for (int mt = 0; mt < 3; ++mt)
      #pragma unroll
      for (int nt = 0; nt < 3; ++nt)
        acc[mt][nt] = __builtin_amdgcn_mfma_f32_16x16x32_bf16(
            af[mt], bfr[nt], acc[mt][nt], 0, 0, 0);
    __syncthreads();
  }
  // scatter per-wave partials to LDS, then reduce 4 waves
  #pragma unroll
  for (int mt = 0; mt < 3; ++mt)
    #pragma unroll
    for (int nt = 0; nt < 3; ++nt)
      #pragma unroll
      for (int r = 0; r < 4; ++r) {
        int i = mt * 16 + ((lane >> 4) << 2) + r;
        int j = nt * 16 + (lane & 15);
        Rs[wid * 2304 + i * 48 + j] = acc[mt][nt][r];
      }
  __syncthreads();
  float* sp = spart + ((size_t)bh * 64 + blockIdx.x) * 2304;
  for (int e = tid; e < 2304; e += 256)
    sp[e] = Rs[e] + Rs[2304 + e] + Rs[2 * 2304 + e] + Rs[3 * 2304 + e];
}

// ---------------------------------------------------------------------------
// Reduce 64 partials, scale, softmax over j. One wave per (bh, i) row.
// ---------------------------------------------------------------------------
__global__ __launch_bounds__(64) void attn_finalize_kernel(
    const float* __restrict__ spart,
    const float* __restrict__ invq, const float* __restrict__ invk,
    const float* __restrict__ temp, float* __restrict__ attn) {
  const int row = blockIdx.x;
  const int bh = row / 48, i = row % 48;
  const int b = bh >> 2, hd = bh & 3;
  const int j = threadIdx.x;
  float s;
  if (j < 48) {
    float t = 0.f;
    for (int c = 0; c < 64; ++c)
      t += spart[((size_t)bh * 64 + c) * 2304 + i * 48 + j];
    s = t * invq[b * Cc + hd * CH + i] * invk[b * Cc + hd * CH + j] * temp[hd];
  } else {
    s = -1e30f;
  }
  float m = s;
  #pragma unroll
  for (int off = 32; off; off >>= 1) m = fmaxf(m, __shfl_xor(m, off));
  float e = (j < 48) ? expf(s - m) : 0.f;
  float sum = e;
  #pragma unroll
  for (int off = 32; off; off >>= 1) sum += __shfl_xor(sum, off);
  if (j < 48) attn[(size_t)bh * 2304 + i * 48 + j] = e / sum;
}

// ---------------------------------------------------------------------------
// out[i][n] = sum_j attn[i][j] * v[j][n]. v bf16 [c][hw].
// TRANS=0: bf16 out [c][hw].  TRANS=1: bf16 out transposed [hw][c].
// ---------------------------------------------------------------------------
template <int TRANS>
__global__ __launch_bounds__(256) void attn_apply_kernel(
    const float* __restrict__ attn,
    const unsigned short* __restrict__ v, size_t vbs,
    unsigned short* __restrict__ out, size_t obs) {
  const int bh = blockIdx.y, b = bh >> 2, hd = bh & 3;
  const int n = blockIdx.x * 256 + threadIdx.x;
  const unsigned short* vp = v + (size_t)b * vbs + (size_t)(hd * CH) * HW + n;
  __shared__ __align__(16) float As[48][48];
  for (int e = threadIdx.x; e < 2304; e += 256)
    As[e / 48][e % 48] = attn[(size_t)bh * 2304 + e];
  __syncthreads();
  float vv[48];
  #pragma unroll
  for (int j = 0; j < 48; ++j) vv[j] = bf2f(vp[(size_t)j * HW]);
  if (TRANS == 0) {
    unsigned short* op = out + (size_t)b * obs + (size_t)(hd * CH) * HW + n;
    #pragma unroll 1
    for (int i = 0; i < 48; ++i) {
      const f32x4* arow = (const f32x4*)&As[i][0];
      float acc = 0.f;
      #pragma unroll
      for (int j4 = 0; j4 < 12; ++j4) {
        f32x4 a = arow[j4];
        acc += a[0] * vv[j4 * 4 + 0] + a[1] * vv[j4 * 4 + 1] +
               a[2] * vv[j4 * 4 + 2] + a[3] * vv[j4 * 4 + 3];
      }
      op[(size_t)i * HW] = f2bf(acc);
    }
  } else {
    unsigned short* tp = out + (size_t)b * CP + (size_t)n * Cc + hd * CH;
    #pragma unroll 1
    for (int io = 0; io < 6; ++io) {
      bf16x8 u;
      #pragma unroll
      for (int e = 0; e < 8; ++e) {
        const f32x4* arow = (const f32x4*)&As[io * 8 + e][0];
        float acc = 0.f;
        #pragma unroll
        for (int j4 = 0; j4 < 12; ++j4) {
          f32x4 a = arow[j4];
          acc += a[0] * vv[j4 * 4 + 0] + a[1] * vv[j4 * 4 + 1] +
                 a[2] * vv[j4 * 4 + 2] + a[3] * vv[j4 * 4 + 3];
        }
        u[e] = f2bf(acc);
      }
      *(bf16x8*)&tp[io * 8] = u;
    }
  }
}

// ---------------------------------------------------------------------------
extern "C" void kernel_launch(void* const* d_in, const int* in_sizes, int n_in,
                              void* d_out, int out_size, void* d_ws, size_t ws_size,
                              hipStream_t stream) {
  const float* x      = (const float*)d_in[0];
  const float* y      = (const float*)d_in[1];
  const float* qkv_w  = (const float*)d_in[2];
  const float* dw_w   = (const float*)d_in[3];
  const float* kv_w   = (const float*)d_in[4];
  const float* proj_w = (const float*)d_in[5];
  const float* temp   = (const float*)d_in[6];
  float* out = (float*)d_out;
  float* ws  = (float*)d_ws;

  const size_t SF = (size_t)Bsz * CP;   // 6,291,456 elements (one [b,192,HW] tensor)
  // layout in float units (bf16 buffers use half)
  unsigned short* qkvb   = (unsigned short*)ws;                       // 3SF shorts -> [0,1.5SF)
  unsigned short* kvb    = (unsigned short*)(ws + 3 * SF / 2);        // 2SF shorts -> [1.5,2.5SF)
  unsigned short* q1b    = (unsigned short*)(ws + 5 * SF / 2);        // SF shorts  -> [2.5,3SF)
  unsigned short* xt     = (unsigned short*)(ws + 3 * SF);            // SF shorts  -> [3,3.5SF)
  unsigned short* o2t    = xt;                                        // reuse (xt dead after qkv conv)
  unsigned short* yt     = (unsigned short*)(ws + 7 * SF / 2);        // SF shorts  -> [3.5,4SF)
  unsigned short* qkvpre = (unsigned short*)(ws + 4 * SF);            // 3SF shorts -> [4,5.5SF)
  float* invq  = ws + 11 * SF / 2;
  float* invk  = invq + Bsz * Cc;
  float* spart = invk + Bsz * Cc;               // 8*64*2304 = 1,179,648 floats
  float* attn  = spart + (size_t)8 * 64 * 2304; // 18,432 floats
  unsigned short* wqkv  = (unsigned short*)(attn + 8 * 2304);
  unsigned short* wkv   = wqkv + 576 * Cc;
  unsigned short* wproj = wkv + 384 * Cc;

  dim3 blk(256);

  // 0. casts
  cast_transpose_kernel<<<dim3(HW / 256, Cc / 8, Bsz), blk, 0, stream>>>(x, xt);
  cast_transpose_kernel<<<dim3(HW / 256, Cc / 8, Bsz), blk, 0, stream>>>(y, yt);
  cast_w_kernel<<<dim3((576 * Cc) / 256), blk, 0, stream>>>(qkv_w, wqkv, 576 * Cc);
  cast_w_kernel<<<dim3((384 * Cc) / 256), blk, 0, stream>>>(kv_w, wkv, 384 * Cc);
  cast_w_kernel<<<dim3((192 * Cc) / 256), blk, 0, stream>>>(proj_w, wproj, 192 * Cc);

  // 1. qkv_pre = conv1x1(x, qkv_w)  -> bf16 [c][hw]
  conv_mfma_kernel<1><<<dim3(HW / BMH, 576 / BNO, Bsz), blk, 0, stream>>>(
      xt, wqkv, qkvpre, 3 * Cc);
  // 2. qkv = dwconv3x3(qkv_pre) -> bf16 [c][hw]
  dwconv_kernel<<<dim3(HW / 2048, 3 * Cc, Bsz), blk, 0, stream>>>(
      qkvpre, dw_w, qkvb, 3 * Cc);
  // 3. kv = conv1x1(y, kv_w) -> bf16 [c][hw]
  conv_mfma_kernel<1><<<dim3(HW / BMH, 384 / BNO, Bsz), blk, 0, stream>>>(
      yt, wkv, kvb, 2 * Cc);

  // 4. mdta1: q = qkvb[0:192], k2 = kvb[0:192], v2 = kvb[192:384]
  norm_kernel<<<dim3(Bsz * Cc), blk, 0, stream>>>(qkvb, 3 * CP, invq);
  norm_kernel<<<dim3(Bsz * Cc), blk, 0, stream>>>(kvb, 2 * CP, invk);
  attn_qk_mfma<<<dim3(64, 8), blk, 0, stream>>>(qkvb, 3 * CP, kvb, 2 * CP, spart);
  attn_finalize_kernel<<<dim3(8 * 48), dim3(64), 0, stream>>>(spart, invq, invk, temp, attn);
  attn_apply_kernel<0><<<dim3(HW / 256, 8), blk, 0, stream>>>(
      attn, kvb + CP, 2 * CP, q1b, CP);

  // 5. mdta2: q = q1b, k = qkvb[192:384], v = qkvb[384:576] -> o2t bf16 [hw][c]
  norm_kernel<<<dim3(Bsz * Cc), blk, 0, stream>>>(q1b, CP, invq);
  norm_kernel<<<dim3(Bsz * Cc), blk, 0, stream>>>(qkvb + CP, 3 * CP, invk);
  attn_qk_mfma<<<dim3(64, 8), blk, 0, stream>>>(q1b, CP, qkvb + CP, 3 * CP, spart);
  attn_finalize_kernel<<<dim3(8 * 48), dim3(64), 0, stream>>>(spart, invq, invk, temp, attn);
  attn_apply_kernel<1><<<dim3(HW / 256, 8), blk, 0, stream>>>(
      attn, qkvb + 2 * CP, 3 * CP, o2t, 0);

  // 6. out = conv1x1(o2t, proj_w) -> fp32
  conv_mfma_kernel<0><<<dim3(HW / BMH, Cc / BNO, Bsz), blk, 0, stream>>>(
      o2t, wproj, out, Cc);
}

// Round 5
// 159.478 us; speedup vs baseline: 3.7361x; 1.1587x over previous
//
#include <hip/hip_runtime.h>
#include <hip/hip_bf16.h>

// Problem constants
#define HW 16384        // 128*128
#define IMGW 128
#define Bsz 2
#define Cc 192          // channels
#define NH 4
#define CH 48
static const size_t CP = (size_t)Cc * HW;   // one batch's 192-channel block

typedef __attribute__((ext_vector_type(4))) float f32x4;
typedef __attribute__((ext_vector_type(8))) short short8;
typedef __attribute__((ext_vector_type(8))) unsigned short bf16x8;
typedef __attribute__((ext_vector_type(4))) unsigned short bf16x4;

__device__ __forceinline__ unsigned short f2bf(float f) {
  __hip_bfloat16 h = __float2bfloat16(f);
  return *reinterpret_cast<unsigned short*>(&h);
}
__device__ __forceinline__ float bf2f(unsigned short u) {
  union { unsigned int i; float f; } v;
  v.i = (unsigned int)u << 16;
  return v.f;
}

// ---------------------------------------------------------------------------
// Cast fp32 [b][192][HW] -> bf16 transposed [b][HW][192] (GEMM A-operand).
// ---------------------------------------------------------------------------
__global__ __launch_bounds__(256) void cast_transpose_kernel(
    const float* __restrict__ in, unsigned short* __restrict__ outt) {
  const int b = blockIdx.z;
  const int c0 = blockIdx.y * 8;
  const int hw = blockIdx.x * 256 + threadIdx.x;
  const float* ib = in + (size_t)b * CP;
  bf16x8 u;
  #pragma unroll
  for (int j = 0; j < 8; ++j)
    u[j] = f2bf(ib[(size_t)(c0 + j) * HW + hw]);
  *(bf16x8*)&outt[(size_t)b * CP + (size_t)hw * Cc + c0] = u;
}

__global__ __launch_bounds__(256) void cast_w_kernel(
    const float* __restrict__ w, unsigned short* __restrict__ wb, int n) {
  int i = blockIdx.x * 256 + threadIdx.x;
  if (i < n) wb[i] = f2bf(w[i]);
}

// ---------------------------------------------------------------------------
// conv1x1 bf16 MFMA GEMM. D[m=hw][n=o] = sum_c Xt[hw][c] * W[o][c]
// Tile 128(hw) x 64(o), 4 waves (2m x 2n). wstride: per-batch weight stride.
// ---------------------------------------------------------------------------
#define BMH 128
#define BNO 64
#define BKC 64
#define PADK 72

template <int OUTBF16>
__global__ __launch_bounds__(256) void conv_mfma_kernel(
    const unsigned short* __restrict__ xt,   // [b][HW][192] bf16
    const unsigned short* __restrict__ wb,   // [Cout][192] bf16 (+ b*wstride)
    void* __restrict__ outv, int Cout, size_t wstride) {
  __shared__ __align__(16) short As[BMH * PADK];
  __shared__ __align__(16) short Bs[BNO * PADK];
  const int b = blockIdx.z;
  const int hw0 = blockIdx.x * BMH;
  const int o0 = blockIdx.y * BNO;
  const int tid = threadIdx.x;
  const int lane = tid & 63, wid = tid >> 6;
  const int wm = wid & 1, wn = wid >> 1;
  const unsigned short* xtb = xt + (size_t)b * CP + (size_t)hw0 * Cc;
  const unsigned short* wbb = wb + (size_t)b * wstride + (size_t)o0 * Cc;
  f32x4 acc[4][2] = {};
  for (int k0 = 0; k0 < Cc; k0 += BKC) {
    #pragma unroll
    for (int p = 0; p < 4; ++p) {
      int i = tid + p * 256;
      int row = i >> 3, cc = i & 7;
      *(short8*)&As[row * PADK + cc * 8] =
          *(const short8*)(xtb + (size_t)row * Cc + k0 + cc * 8);
    }
    #pragma unroll
    for (int p = 0; p < 2; ++p) {
      int i = tid + p * 256;
      int row = i >> 3, cc = i & 7;
      *(short8*)&Bs[row * PADK + cc * 8] =
          *(const short8*)(wbb + (size_t)row * Cc + k0 + cc * 8);
    }
    __syncthreads();
    #pragma unroll
    for (int ks = 0; ks < 2; ++ks) {
      short8 bfrag[2];
      #pragma unroll
      for (int fn = 0; fn < 2; ++fn)
        bfrag[fn] = *(short8*)&Bs[(wn * 32 + fn * 16 + (lane & 15)) * PADK +
                                  ks * 32 + (lane >> 4) * 8];
      #pragma unroll
      for (int fm = 0; fm < 4; ++fm) {
        short8 afrag = *(short8*)&As[(wm * 64 + fm * 16 + (lane & 15)) * PADK +
                                     ks * 32 + (lane >> 4) * 8];
        #pragma unroll
        for (int fn = 0; fn < 2; ++fn)
          acc[fm][fn] = __builtin_amdgcn_mfma_f32_16x16x32_bf16(
              afrag, bfrag[fn], acc[fm][fn], 0, 0, 0);
      }
    }
    __syncthreads();
  }
  #pragma unroll
  for (int fm = 0; fm < 4; ++fm)
    #pragma unroll
    for (int fn = 0; fn < 2; ++fn) {
      int o = o0 + wn * 32 + fn * 16 + (lane & 15);
      int hw = hw0 + wm * 64 + fm * 16 + ((lane >> 4) << 2);
      if (OUTBF16) {
        bf16x4 u;
        #pragma unroll
        for (int r = 0; r < 4; ++r) u[r] = f2bf(acc[fm][fn][r]);
        *(bf16x4*)&((unsigned short*)outv)[((size_t)b * Cout + o) * HW + hw] = u;
      } else {
        *(f32x4*)&((float*)outv)[((size_t)b * Cout + o) * HW + hw] = acc[fm][fn];
      }
    }
}

// ---------------------------------------------------------------------------
// depthwise 3x3 SAME, bf16 in/out, fp32 accum. 8 px/thread.
// ---------------------------------------------------------------------------
__global__ __launch_bounds__(256) void dwconv_kernel(
    const unsigned short* __restrict__ in, const float* __restrict__ wgt,
    unsigned short* __restrict__ out, int Ctot) {
  const int b = blockIdx.z, ch = blockIdx.y;
  const int p0 = blockIdx.x * 2048 + threadIdx.x * 8;
  const int y = p0 >> 7, x0 = p0 & 127;
  const unsigned short* ip = in + ((size_t)b * Ctot + ch) * HW;
  const float* wp = wgt + ch * 9;
  float acc[8] = {};
  #pragma unroll
  for (int dy = -1; dy <= 1; ++dy) {
    int yy = y + dy;
    if (yy < 0 || yy > IMGW - 1) continue;
    const unsigned short* rp = ip + yy * IMGW;
    float r[10];
    bf16x8 mid = *(const bf16x8*)&rp[x0];
    #pragma unroll
    for (int e = 0; e < 8; ++e) r[e + 1] = bf2f(mid[e]);
    r[0] = (x0 > 0) ? bf2f(rp[x0 - 1]) : 0.f;
    r[9] = (x0 < 120) ? bf2f(rp[x0 + 8]) : 0.f;
    #pragma unroll
    for (int dx = 0; dx < 3; ++dx) {
      float wv = wp[(dy + 1) * 3 + dx];
      #pragma unroll
      for (int e = 0; e < 8; ++e) acc[e] += wv * r[e + dx];
    }
  }
  bf16x8 u;
  #pragma unroll
  for (int e = 0; e < 8; ++e) u[e] = f2bf(acc[e]);
  *(bf16x8*)&out[((size_t)b * Ctot + ch) * HW + p0] = u;
}

// ---------------------------------------------------------------------------
// L2 norm over HW per (b, channel): inv = 1/max(||x||,1e-12), bf16 input.
// ---------------------------------------------------------------------------
__global__ __launch_bounds__(256) void norm_kernel(
    const unsigned short* __restrict__ in, size_t bstride,
    float* __restrict__ inv) {
  const int row = blockIdx.x;
  const int b = row / Cc, r = row % Cc;
  const unsigned short* p = in + (size_t)b * bstride + (size_t)r * HW;
  float s = 0.f;
  for (int i = threadIdx.x * 8; i < HW; i += 2048) {
    bf16x8 u = *(const bf16x8*)&p[i];
    #pragma unroll
    for (int j = 0; j < 8; ++j) {
      float v = bf2f(u[j]);
      s += v * v;
    }
  }
  #pragma unroll
  for (int off = 32; off; off >>= 1) s += __shfl_down(s, off);
  __shared__ float red[4];
  if ((threadIdx.x & 63) == 0) red[threadIdx.x >> 6] = s;
  __syncthreads();
  if (threadIdx.x == 0) {
    float t = red[0] + red[1] + red[2] + red[3];
    inv[row] = 1.f / fmaxf(sqrtf(t), 1e-12f);
  }
}

// ---------------------------------------------------------------------------
// Gram partials via MFMA: G[i][j] += sum_n A[i][n]*B[j][n].
// grid (32 chunks, 8 bh); chunk = 512 n, 4 iters of 128.
// ---------------------------------------------------------------------------
#define PK 136
__global__ __launch_bounds__(256) void gram_mfma_kernel(
    const unsigned short* __restrict__ q, size_t qbs,
    const unsigned short* __restrict__ k, size_t kbs,
    float* __restrict__ spart) {
  __shared__ __align__(16) char lds_raw[4 * 2304 * 4];
  short* Qs = (short*)lds_raw;
  short* Ks = Qs + 48 * PK;
  float* Rs = (float*)lds_raw;
  const int bh = blockIdx.y, b = bh >> 2, hd = bh & 3;
  const int n0 = blockIdx.x * 512;
  const int tid = threadIdx.x, lane = tid & 63, wid = tid >> 6;
  const unsigned short* qb = q + (size_t)b * qbs + (size_t)(hd * CH) * HW + n0;
  const unsigned short* kb = k + (size_t)b * kbs + (size_t)(hd * CH) * HW + n0;
  f32x4 acc[3][3] = {};
  #pragma unroll 1
  for (int it = 0; it < 4; ++it) {
    #pragma unroll
    for (int p = 0; p < 3; ++p) {
      int c = tid + p * 256;
      int row = c >> 4, col = c & 15;
      *(short8*)&Qs[row * PK + col * 8] =
          *(const short8*)(qb + (size_t)row * HW + it * 128 + col * 8);
      *(short8*)&Ks[row * PK + col * 8] =
          *(const short8*)(kb + (size_t)row * HW + it * 128 + col * 8);
    }
    __syncthreads();
    short8 af[3], bfr[3];
    #pragma unroll
    for (int t = 0; t < 3; ++t) {
      af[t]  = *(short8*)&Qs[(t * 16 + (lane & 15)) * PK + wid * 32 + (lane >> 4) * 8];
      bfr[t] = *(short8*)&Ks[(t * 16 + (lane & 15)) * PK + wid * 32 + (lane >> 4) * 8];
    }
    #pragma unroll
    for (int mt = 0; mt < 3; ++mt)
      #pragma unroll
      for (int nt = 0; nt < 3; ++nt)
        acc[mt][nt] = __builtin_amdgcn_mfma_f32_16x16x32_bf16(
            af[mt], bfr[nt], acc[mt][nt], 0, 0, 0);
    __syncthreads();
  }
  #pragma unroll
  for (int mt = 0; mt < 3; ++mt)
    #pragma unroll
    for (int nt = 0; nt < 3; ++nt)
      #pragma unroll
      for (int r = 0; r < 4; ++r) {
        int i = mt * 16 + ((lane >> 4) << 2) + r;
        int j = nt * 16 + (lane & 15);
        Rs[wid * 2304 + i * 48 + j] = acc[mt][nt][r];
      }
  __syncthreads();
  float* sp = spart + ((size_t)bh * 32 + blockIdx.x) * 2304;
  for (int e = tid; e < 2304; e += 256)
    sp[e] = Rs[e] + Rs[2304 + e] + Rs[2 * 2304 + e] + Rs[3 * 2304 + e];
}

// ---------------------------------------------------------------------------
// Reduce 32 chunk-partials for all 3 Gram pairs: G[pair][bh][2304].
// flat over 3*8*2304 = 55296 -> 216 blocks.
// ---------------------------------------------------------------------------
__global__ __launch_bounds__(256) void gram_reduce_kernel(
    const float* __restrict__ spart, float* __restrict__ G) {
  int idx = blockIdx.x * 256 + threadIdx.x;
  if (idx >= 3 * 8 * 2304) return;
  int pb = idx / 2304;        // pair*8 + bh
  int e = idx - pb * 2304;
  const float* sp = spart + ((size_t)pb * 32) * 2304 + e;
  float s = 0.f;
  #pragma unroll 8
  for (int c = 0; c < 32; ++c) s += sp[(size_t)c * 2304];
  G[idx] = s;
}

// ---------------------------------------------------------------------------
// Per-bh finalize: S1 softmax -> A1; ||q1|| via A1*Gvv*A1^T; S2 = A1*Gvk
// scaled; softmax -> A2. One block per bh.
// G layout: pair0=Q*K2^T, pair1=V2*K^T, pair2=V2*V2^T, each [8][2304].
// ---------------------------------------------------------------------------
__global__ __launch_bounds__(256) void attn2_finalize_kernel(
    const float* __restrict__ G,
    const float* __restrict__ invQ, const float* __restrict__ invK2,
    const float* __restrict__ invK, const float* __restrict__ temp,
    float* __restrict__ attn2) {
  __shared__ float G1[2304], Gvk[2304], Gvv[2304], A1[2304], T[2304], S[2304];
  __shared__ float invq1[48];
  const int bh = blockIdx.x, b = bh >> 2, hd = bh & 3;
  const int tid = threadIdx.x;
  for (int e = tid; e < 2304; e += 256) {
    G1[e]  = G[(size_t)(0 * 8 + bh) * 2304 + e];
    Gvk[e] = G[(size_t)(1 * 8 + bh) * 2304 + e];
    Gvv[e] = G[(size_t)(2 * 8 + bh) * 2304 + e];
  }
  __syncthreads();
  const float tp = temp[hd];
  // S1 scaled
  for (int e = tid; e < 2304; e += 256) {
    int i = e / 48, j = e - i * 48;
    S[e] = G1[e] * invQ[b * Cc + hd * CH + i] * invK2[b * Cc + hd * CH + j] * tp;
  }
  __syncthreads();
  if (tid < 48) {
    float m = -1e30f;
    for (int j = 0; j < 48; ++j) m = fmaxf(m, S[tid * 48 + j]);
    float sum = 0.f;
    for (int j = 0; j < 48; ++j) {
      float e2 = expf(S[tid * 48 + j] - m);
      A1[tid * 48 + j] = e2;
      sum += e2;
    }
    float r = 1.f / sum;
    for (int j = 0; j < 48; ++j) A1[tid * 48 + j] *= r;
  }
  __syncthreads();
  // T = A1 * Gvv
  for (int e = tid; e < 2304; e += 256) {
    int i = e / 48, j = e - i * 48;
    float s = 0.f;
    #pragma unroll 8
    for (int d = 0; d < 48; ++d) s += A1[i * 48 + d] * Gvv[d * 48 + j];
    T[e] = s;
  }
  __syncthreads();
  if (tid < 48) {
    float s = 0.f;
    for (int j = 0; j < 48; ++j) s += T[tid * 48 + j] * A1[tid * 48 + j];
    invq1[tid] = 1.f / fmaxf(sqrtf(fmaxf(s, 0.f)), 1e-12f);
  }
  __syncthreads();
  // S2 = invq1 * (A1 * Gvk) * invK * tp
  for (int e = tid; e < 2304; e += 256) {
    int i = e / 48, j = e - i * 48;
    float s = 0.f;
    #pragma unroll 8
    for (int d = 0; d < 48; ++d) s += A1[i * 48 + d] * Gvk[d * 48 + j];
    S[e] = s * invq1[i] * invK[b * Cc + hd * CH + j] * tp;
  }
  __syncthreads();
  if (tid < 48) {
    float m = -1e30f;
    for (int j = 0; j < 48; ++j) m = fmaxf(m, S[tid * 48 + j]);
    float sum = 0.f;
    for (int j = 0; j < 48; ++j) {
      float e2 = expf(S[tid * 48 + j] - m);
      T[tid * 48 + j] = e2;
      sum += e2;
    }
    float r = 1.f / sum;
    for (int j = 0; j < 48; ++j)
      attn2[(size_t)bh * 2304 + tid * 48 + j] = T[tid * 48 + j] * r;
  }
}

// ---------------------------------------------------------------------------
// M[b][o][c] = sum_i P[o][hd*48+i] * A2[b][hd][i][c%48],  hd = c/48 (bf16 out)
// ---------------------------------------------------------------------------
__global__ __launch_bounds__(192) void mproj_kernel(
    const float* __restrict__ P, const float* __restrict__ attn2,
    unsigned short* __restrict__ Mb) {
  const int b = blockIdx.y, o = blockIdx.x;
  const int c = threadIdx.x;
  const int hd = c / 48, j = c - hd * 48;
  const float* prow = P + (size_t)o * Cc + hd * 48;
  const float* arow = attn2 + (size_t)(b * 4 + hd) * 2304 + j;
  float s = 0.f;
  #pragma unroll 8
  for (int i = 0; i < 48; ++i) s += prow[i] * arow[(size_t)i * 48];
  Mb[((size_t)b * Cc + o) * Cc + c] = f2bf(s);
}

// ---------------------------------------------------------------------------
// Transpose bf16 [c][hw] (stride vbs per batch) -> [b][hw][192] for c0..c0+63.
// ---------------------------------------------------------------------------
__global__ __launch_bounds__(256) void vtrans_kernel(
    const unsigned short* __restrict__ v, size_t vbs,
    unsigned short* __restrict__ vt) {
  __shared__ unsigned short LT[64 * 65];
  const int b = blockIdx.z;
  const int c0 = blockIdx.y * 64;
  const int h0 = blockIdx.x * 64;
  const int tid = threadIdx.x;
  const unsigned short* ip = v + (size_t)b * vbs + (size_t)c0 * HW + h0;
  #pragma unroll
  for (int e = 0; e < 2; ++e) {
    int idx = e * 256 + tid;             // 0..511
    int c = idx >> 3, hg = idx & 7;
    bf16x8 r = *(const bf16x8*)(ip + (size_t)c * HW + hg * 8);
    #pragma unroll
    for (int j = 0; j < 8; ++j) LT[c * 65 + hg * 8 + j] = r[j];
  }
  __syncthreads();
  unsigned short* op = vt + (size_t)b * CP + (size_t)h0 * Cc + c0;
  #pragma unroll
  for (int e = 0; e < 2; ++e) {
    int idx = e * 256 + tid;
    int hw = idx >> 3, cg = idx & 7;
    bf16x8 u;
    #pragma unroll
    for (int j = 0; j < 8; ++j) u[j] = LT[(cg * 8 + j) * 65 + hw];
    *(bf16x8*)&op[(size_t)hw * Cc + cg * 8] = u;
  }
}

// ---------------------------------------------------------------------------
extern "C" void kernel_launch(void* const* d_in, const int* in_sizes, int n_in,
                              void* d_out, int out_size, void* d_ws, size_t ws_size,
                              hipStream_t stream) {
  const float* x      = (const float*)d_in[0];
  const float* y      = (const float*)d_in[1];
  const float* qkv_w  = (const float*)d_in[2];
  const float* dw_w   = (const float*)d_in[3];
  const float* kv_w   = (const float*)d_in[4];
  const float* proj_w = (const float*)d_in[5];
  const float* temp   = (const float*)d_in[6];
  float* out = (float*)d_out;
  float* ws  = (float*)d_ws;

  const size_t SF = (size_t)Bsz * CP;   // 6,291,456 elements
  unsigned short* qkvb   = (unsigned short*)ws;                 // 3SF shorts
  unsigned short* kvb    = (unsigned short*)(ws + 3 * SF / 2);  // 2SF shorts
  unsigned short* xt     = (unsigned short*)(ws + 5 * SF / 2);  // SF shorts
  unsigned short* yt     = (unsigned short*)(ws + 3 * SF);      // SF shorts
  unsigned short* qkvpre = (unsigned short*)(ws + 7 * SF / 2);  // 3SF shorts
  unsigned short* vt     = (unsigned short*)(ws + 5 * SF);      // SF shorts
  float* invq  = ws + 11 * SF / 2;
  float* invk2 = invq + Bsz * Cc;
  float* invk  = invk2 + Bsz * Cc;
  float* spart = invk + Bsz * Cc;                   // 3*8*32*2304 floats
  float* G     = spart + (size_t)3 * 8 * 32 * 2304; // 3*8*2304
  float* attn2 = G + 3 * 8 * 2304;                  // 8*2304
  unsigned short* wqkv = (unsigned short*)(attn2 + 8 * 2304);
  unsigned short* wkv  = wqkv + 576 * Cc;
  unsigned short* Mb   = wkv + 384 * Cc;            // 2*192*192 bf16

  dim3 blk(256);
  const size_t GSZ = (size_t)8 * 32 * 2304;

  // 0. casts
  cast_transpose_kernel<<<dim3(HW / 256, Cc / 8, Bsz), blk, 0, stream>>>(x, xt);
  cast_transpose_kernel<<<dim3(HW / 256, Cc / 8, Bsz), blk, 0, stream>>>(y, yt);
  cast_w_kernel<<<dim3((576 * Cc) / 256), blk, 0, stream>>>(qkv_w, wqkv, 576 * Cc);
  cast_w_kernel<<<dim3((384 * Cc) / 256), blk, 0, stream>>>(kv_w, wkv, 384 * Cc);

  // 1. qkv_pre = conv1x1(x, qkv_w) -> bf16 [c][hw]
  conv_mfma_kernel<1><<<dim3(HW / BMH, 576 / BNO, Bsz), blk, 0, stream>>>(
      xt, wqkv, qkvpre, 3 * Cc, 0);
  // 2. qkv = dwconv3x3(qkv_pre)
  dwconv_kernel<<<dim3(HW / 2048, 3 * Cc, Bsz), blk, 0, stream>>>(
      qkvpre, dw_w, qkvb, 3 * Cc);
  // 3. kv = conv1x1(y, kv_w)
  conv_mfma_kernel<1><<<dim3(HW / BMH, 384 / BNO, Bsz), blk, 0, stream>>>(
      yt, wkv, kvb, 2 * Cc, 0);

  // 4. norms: Q (qkv slice 0), K2 (kv slice 0), K (qkv slice 1)
  norm_kernel<<<dim3(Bsz * Cc), blk, 0, stream>>>(qkvb, 3 * CP, invq);
  norm_kernel<<<dim3(Bsz * Cc), blk, 0, stream>>>(kvb, 2 * CP, invk2);
  norm_kernel<<<dim3(Bsz * Cc), blk, 0, stream>>>(qkvb + CP, 3 * CP, invk);

  // 5. Gram partials: (Q,K2), (V2,K), (V2,V2)
  gram_mfma_kernel<<<dim3(32, 8), blk, 0, stream>>>(
      qkvb, 3 * CP, kvb, 2 * CP, spart);
  gram_mfma_kernel<<<dim3(32, 8), blk, 0, stream>>>(
      kvb + CP, 2 * CP, qkvb + CP, 3 * CP, spart + GSZ);
  gram_mfma_kernel<<<dim3(32, 8), blk, 0, stream>>>(
      kvb + CP, 2 * CP, kvb + CP, 2 * CP, spart + 2 * GSZ);

  // 6. reduce + finalize -> A2, then M = P * A2_blockdiag
  gram_reduce_kernel<<<dim3(216), blk, 0, stream>>>(spart, G);
  attn2_finalize_kernel<<<dim3(8), blk, 0, stream>>>(
      G, invq, invk2, invk, temp, attn2);
  mproj_kernel<<<dim3(Cc, Bsz), dim3(192), 0, stream>>>(proj_w, attn2, Mb);

  // 7. out = M * V  (V = qkv slice 2, transposed to [hw][c] first)
  vtrans_kernel<<<dim3(HW / 64, Cc / 64, Bsz), blk, 0, stream>>>(
      qkvb + 2 * CP, 3 * CP, vt);
  conv_mfma_kernel<0><<<dim3(HW / BMH, Cc / BNO, Bsz), blk, 0, stream>>>(
      vt, Mb, out, Cc, (size_t)Cc * Cc);
}